// Round 1
// baseline (2742.118 us; speedup 1.0000x reference)
//
#include <hip/hip_runtime.h>

#define N_NODES 50000
#define N_EDGES 1600000
#define NREL 32
#define NBASES 8
#define DIN 128
#define DOUT 128
#define KTOT (NBASES * DIN)     // 1024
#define NODES_PER_BLOCK 8
#define KCHUNK 64

// ---------------- CSR build ----------------

__global__ void k_hist(const int* __restrict__ dst, int* __restrict__ deg) {
    int e = blockIdx.x * blockDim.x + threadIdx.x;
    if (e < N_EDGES) atomicAdd(&deg[dst[e]], 1);
}

__global__ void k_scan(const int* __restrict__ deg, int* __restrict__ indptr) {
    // single block, 1024 threads: chunked serial sums + Hillis-Steele block scan
    __shared__ int sdata[1024];
    const int T = 1024;
    int t = threadIdx.x;
    const int chunk = (N_NODES + T - 1) / T;   // 49
    int lo = t * chunk;
    int hi = lo + chunk; if (hi > N_NODES) hi = N_NODES;
    if (lo > N_NODES) lo = N_NODES;
    int s = 0;
    for (int i = lo; i < hi; ++i) s += deg[i];
    sdata[t] = s;
    __syncthreads();
    for (int off = 1; off < T; off <<= 1) {
        int v = (t >= off) ? sdata[t - off] : 0;
        __syncthreads();
        sdata[t] += v;
        __syncthreads();
    }
    int base = (t == 0) ? 0 : sdata[t - 1];
    for (int i = lo; i < hi; ++i) { indptr[i] = base; base += deg[i]; }
    if (t == T - 1) indptr[N_NODES] = sdata[T - 1];   // == E
}

__global__ void k_scatter(const int* __restrict__ dst,
                          const int* __restrict__ indptr,
                          int* __restrict__ cursor,
                          int* __restrict__ eids) {
    int e = blockIdx.x * blockDim.x + threadIdx.x;
    if (e < N_EDGES) {
        int d = dst[e];
        int pos = atomicAdd(&cursor[d], 1);
        eids[indptr[d] + pos] = e;
    }
}

// ---------------- fused aggregate + project ----------------
// Block: 256 threads, handles 8 dst nodes.
//  Phase 1: per node, acc[b][d] = sum over in-edges of w_comp[et][b]*x[src][d]
//           (thread = (half, d); 2 nodes in parallel, 4 passes) -> LDS tmp
//  Phase 2: h[node][dout] = sum_k tmp[node][k]*weight[k][dout], weight staged
//           in LDS 64-row chunks; thread (half,d) accumulates 4 nodes.
//  Epilogue: + bias + x@loop_weight, ReLU.

__launch_bounds__(256, 2)
__global__ void k_fused(const float* __restrict__ x,
                        const int* __restrict__ src,
                        const int* __restrict__ etypes,
                        const float* __restrict__ weight,    // [K=1024][DOUT]
                        const float* __restrict__ w_comp,    // [R][B]
                        const float* __restrict__ h_bias,    // [DOUT]
                        const float* __restrict__ loop_w,    // [DIN][DOUT]
                        const int* __restrict__ indptr,
                        const int* __restrict__ eids,
                        float* __restrict__ out) {
    __shared__ float wc[NREL * NBASES];                      // 1 KB
    __shared__ float tmp[NODES_PER_BLOCK][KTOT];             // 32 KB
    __shared__ float wch[KCHUNK * DOUT];                     // 32 KB

    const int tid = threadIdx.x;
    const int d = tid & 127;
    const int half = tid >> 7;           // 0 or 1
    const int nbase = blockIdx.x * NODES_PER_BLOCK;

    if (tid < NREL * NBASES) wc[tid] = w_comp[tid];
    __syncthreads();

    // ---- Phase 1: aggregation ----
    for (int p = 0; p < 4; ++p) {
        const int nl = p * 2 + half;
        const int node = nbase + nl;
        float acc[NBASES];
        #pragma unroll
        for (int b = 0; b < NBASES; ++b) acc[b] = 0.f;
        if (node < N_NODES) {
            const int beg = indptr[node], end = indptr[node + 1];
            for (int i = beg; i < end; ++i) {
                const int e  = eids[i];
                const int s  = src[e];
                const int et = etypes[e];
                const float xv = x[s * DIN + d];
                const float* wcr = &wc[et * NBASES];
                #pragma unroll
                for (int b = 0; b < NBASES; ++b) acc[b] += wcr[b] * xv;
            }
        }
        #pragma unroll
        for (int b = 0; b < NBASES; ++b) tmp[nl][b * DIN + d] = acc[b];
    }
    __syncthreads();

    // ---- Phase 2: projection GEMM  [8 x 1024] @ [1024 x 128] ----
    float o[4] = {0.f, 0.f, 0.f, 0.f};   // nodes half, half+2, half+4, half+6
    for (int kc = 0; kc < KTOT / KCHUNK; ++kc) {
        #pragma unroll
        for (int j = 0; j < (KCHUNK * DOUT) / 256; ++j) {
            const int idx = j * 256 + tid;
            wch[idx] = weight[kc * KCHUNK * DOUT + idx];
        }
        __syncthreads();
        for (int k = 0; k < KCHUNK; ++k) {
            const float wv = wch[k * DOUT + d];
            #pragma unroll
            for (int j = 0; j < 4; ++j)
                o[j] += tmp[half + 2 * j][kc * KCHUNK + k] * wv;
        }
        __syncthreads();
    }

    // ---- Epilogue: bias + self-loop + ReLU ----
    const float bias = h_bias[d];
    float sl[4] = {0.f, 0.f, 0.f, 0.f};
    for (int k = 0; k < DIN; ++k) {
        const float lw = loop_w[k * DOUT + d];
        #pragma unroll
        for (int j = 0; j < 4; ++j)
            sl[j] += x[(nbase + half + 2 * j) * DIN + k] * lw;
    }
    #pragma unroll
    for (int j = 0; j < 4; ++j) {
        const int node = nbase + half + 2 * j;
        if (node < N_NODES)
            out[node * DOUT + d] = fmaxf(o[j] + bias + sl[j], 0.f);
    }
}

// ---------------- launch ----------------

extern "C" void kernel_launch(void* const* d_in, const int* in_sizes, int n_in,
                              void* d_out, int out_size, void* d_ws, size_t ws_size,
                              hipStream_t stream) {
    const float* x      = (const float*)d_in[0];
    const int*   src    = (const int*)  d_in[1];
    const int*   dst    = (const int*)  d_in[2];
    const int*   ety    = (const int*)  d_in[3];
    const float* weight = (const float*)d_in[4];
    const float* w_comp = (const float*)d_in[5];
    const float* h_bias = (const float*)d_in[6];
    const float* loop_w = (const float*)d_in[7];
    float* out = (float*)d_out;

    int* deg    = (int*)d_ws;                 // N
    int* indptr = deg + N_NODES;              // N+1
    int* cursor = indptr + N_NODES + 1;       // N
    int* eids   = cursor + N_NODES;           // E

    // zero deg + indptr + cursor in one shot (indptr overwritten by scan anyway)
    hipMemsetAsync(d_ws, 0, (size_t)(3 * N_NODES + 1) * sizeof(int), stream);

    k_hist<<<(N_EDGES + 255) / 256, 256, 0, stream>>>(dst, deg);
    k_scan<<<1, 1024, 0, stream>>>(deg, indptr);
    k_scatter<<<(N_EDGES + 255) / 256, 256, 0, stream>>>(dst, indptr, cursor, eids);
    k_fused<<<(N_NODES + NODES_PER_BLOCK - 1) / NODES_PER_BLOCK, 256, 0, stream>>>(
        x, src, ety, weight, w_comp, h_bias, loop_w, indptr, eids, out);
}

// Round 3
// 2296.680 us; speedup vs baseline: 1.1939x; 1.1939x over previous
//
#include <hip/hip_runtime.h>

#define N_NODES 50000
#define N_EDGES 1600000
#define NREL 32
#define NBASES 8
#define DIN 128
#define DOUT 128
#define KTOT (NBASES * DIN)       // 1024
#define KSL (KTOT + DIN)          // 1152 (self-loop folded in)
#define NODES_PER_BLOCK 8

// ---------------- CSR build ----------------

__global__ void k_hist(const int* __restrict__ dst, int* __restrict__ deg) {
    int e = blockIdx.x * blockDim.x + threadIdx.x;
    if (e < N_EDGES) atomicAdd(&deg[dst[e]], 1);
}

__global__ void k_scan(const int* __restrict__ deg, int* __restrict__ indptr) {
    __shared__ int sdata[1024];
    const int T = 1024;
    int t = threadIdx.x;
    const int chunk = (N_NODES + T - 1) / T;
    int lo = t * chunk;
    int hi = lo + chunk; if (hi > N_NODES) hi = N_NODES;
    if (lo > N_NODES) lo = N_NODES;
    int s = 0;
    for (int i = lo; i < hi; ++i) s += deg[i];
    sdata[t] = s;
    __syncthreads();
    for (int off = 1; off < T; off <<= 1) {
        int v = (t >= off) ? sdata[t - off] : 0;
        __syncthreads();
        sdata[t] += v;
        __syncthreads();
    }
    int base = (t == 0) ? 0 : sdata[t - 1];
    for (int i = lo; i < hi; ++i) { indptr[i] = base; base += deg[i]; }
    if (t == T - 1) indptr[N_NODES] = sdata[T - 1];
}

// writes dst-sorted packed records: src | (etype << 16)
__global__ void k_scatter(const int* __restrict__ dst,
                          const int* __restrict__ src,
                          const int* __restrict__ ety,
                          const int* __restrict__ indptr,
                          int* __restrict__ cursor,
                          int* __restrict__ packed) {
    int e = blockIdx.x * blockDim.x + threadIdx.x;
    if (e < N_EDGES) {
        int d = dst[e];
        int pos = atomicAdd(&cursor[d], 1);
        packed[indptr[d] + pos] = src[e] | (ety[e] << 16);
    }
}

// ---------------- fused aggregate + project ----------------
// Block: 256 threads (4 waves), 8 dst nodes.
// Phase 1: wave w aggregates nodes {w, w+4}; lane covers d=2*lane,2*lane+1
//          (float2). Edge records loaded cooperatively 64-wide, broadcast
//          via __shfl; x gathers batched 4-wide for MLP. Also stashes the
//          node's own x row at tmp[][1024..1151] for the self-loop.
// Phase 2: h = tmp[8 x 1152] @ [weight;loop_w][1152 x 128], weight read
//          straight from L2 (coalesced), tmp via LDS broadcast float4.

__launch_bounds__(256, 4)
__global__ void k_fused(const float* __restrict__ x,
                        const float* __restrict__ weight,    // [1024][128]
                        const float* __restrict__ w_comp,    // [32][8]
                        const float* __restrict__ h_bias,    // [128]
                        const float* __restrict__ loop_w,    // [128][128]
                        const int* __restrict__ indptr,
                        const int* __restrict__ packed,
                        float* __restrict__ out) {
    __shared__ __align__(16) float wc[NREL * NBASES];            // 1 KB
    __shared__ __align__(16) float tmp[NODES_PER_BLOCK][KSL];    // 36 KB

    const int tid  = threadIdx.x;
    const int lane = tid & 63;
    const int wid  = tid >> 6;                 // 0..3
    const int nbase = blockIdx.x * NODES_PER_BLOCK;

    if (tid < NREL * NBASES) wc[tid] = w_comp[tid];
    __syncthreads();

    // ---- Phase 1 ----
    for (int rep = 0; rep < 2; ++rep) {
        const int nl = wid + rep * 4;
        const int node = nbase + nl;
        float2 acc[NBASES];
        #pragma unroll
        for (int b = 0; b < NBASES; ++b) acc[b] = make_float2(0.f, 0.f);

        if (node < N_NODES) {
            // self-loop row into LDS
            *(float2*)&tmp[nl][KTOT + 2 * lane] =
                *(const float2*)&x[(size_t)node * DIN + 2 * lane];

            const int beg = indptr[node], end = indptr[node + 1];
            for (int base = beg; base < end; base += 64) {
                const int cnt = min(64, end - base);
                int pk = 0;
                if (base + lane < end) pk = packed[base + lane];
                int j = 0;
                for (; j + 4 <= cnt; j += 4) {
                    int p[4];
                    #pragma unroll
                    for (int u = 0; u < 4; ++u) p[u] = __shfl(pk, j + u);
                    float2 xv[4]; float4 wA[4], wB[4];
                    #pragma unroll
                    for (int u = 0; u < 4; ++u) {
                        xv[u] = *(const float2*)&x[(size_t)(p[u] & 0xFFFF) * DIN + 2 * lane];
                        wA[u] = *(const float4*)&wc[(p[u] >> 16) * NBASES];
                        wB[u] = *(const float4*)&wc[(p[u] >> 16) * NBASES + 4];
                    }
                    #pragma unroll
                    for (int u = 0; u < 4; ++u) {
                        acc[0].x += wA[u].x * xv[u].x; acc[0].y += wA[u].x * xv[u].y;
                        acc[1].x += wA[u].y * xv[u].x; acc[1].y += wA[u].y * xv[u].y;
                        acc[2].x += wA[u].z * xv[u].x; acc[2].y += wA[u].z * xv[u].y;
                        acc[3].x += wA[u].w * xv[u].x; acc[3].y += wA[u].w * xv[u].y;
                        acc[4].x += wB[u].x * xv[u].x; acc[4].y += wB[u].x * xv[u].y;
                        acc[5].x += wB[u].y * xv[u].x; acc[5].y += wB[u].y * xv[u].y;
                        acc[6].x += wB[u].z * xv[u].x; acc[6].y += wB[u].z * xv[u].y;
                        acc[7].x += wB[u].w * xv[u].x; acc[7].y += wB[u].w * xv[u].y;
                    }
                }
                for (; j < cnt; ++j) {
                    const int p0 = __shfl(pk, j);
                    const float2 xv = *(const float2*)&x[(size_t)(p0 & 0xFFFF) * DIN + 2 * lane];
                    const float4 wA = *(const float4*)&wc[(p0 >> 16) * NBASES];
                    const float4 wB = *(const float4*)&wc[(p0 >> 16) * NBASES + 4];
                    acc[0].x += wA.x * xv.x; acc[0].y += wA.x * xv.y;
                    acc[1].x += wA.y * xv.x; acc[1].y += wA.y * xv.y;
                    acc[2].x += wA.z * xv.x; acc[2].y += wA.z * xv.y;
                    acc[3].x += wA.w * xv.x; acc[3].y += wA.w * xv.y;
                    acc[4].x += wB.x * xv.x; acc[4].y += wB.x * xv.y;
                    acc[5].x += wB.y * xv.x; acc[5].y += wB.y * xv.y;
                    acc[6].x += wB.z * xv.x; acc[6].y += wB.z * xv.y;
                    acc[7].x += wB.w * xv.x; acc[7].y += wB.w * xv.y;
                }
            }
        }
        #pragma unroll
        for (int b = 0; b < NBASES; ++b)
            *(float2*)&tmp[nl][b * DIN + 2 * lane] = acc[b];
    }
    __syncthreads();

    // ---- Phase 2: [8 x 1152] @ [1152 x 128] ----
    const int d = tid & 127;
    const int half = tid >> 7;
    float o[4] = {0.f, 0.f, 0.f, 0.f};     // nodes half, half+2, half+4, half+6

    for (int k = 0; k < KTOT; k += 4) {
        const float wv0 = weight[(k + 0) * DOUT + d];
        const float wv1 = weight[(k + 1) * DOUT + d];
        const float wv2 = weight[(k + 2) * DOUT + d];
        const float wv3 = weight[(k + 3) * DOUT + d];
        #pragma unroll
        for (int j = 0; j < 4; ++j) {
            const float4 t = *(const float4*)&tmp[half + 2 * j][k];
            o[j] += t.x * wv0 + t.y * wv1 + t.z * wv2 + t.w * wv3;
        }
    }
    for (int k = 0; k < DIN; k += 4) {
        const float wv0 = loop_w[(k + 0) * DOUT + d];
        const float wv1 = loop_w[(k + 1) * DOUT + d];
        const float wv2 = loop_w[(k + 2) * DOUT + d];
        const float wv3 = loop_w[(k + 3) * DOUT + d];
        #pragma unroll
        for (int j = 0; j < 4; ++j) {
            const float4 t = *(const float4*)&tmp[half + 2 * j][KTOT + k];
            o[j] += t.x * wv0 + t.y * wv1 + t.z * wv2 + t.w * wv3;
        }
    }

    const float bias = h_bias[d];
    #pragma unroll
    for (int j = 0; j < 4; ++j) {
        const int node = nbase + half + 2 * j;
        if (node < N_NODES)
            out[(size_t)node * DOUT + d] = fmaxf(o[j] + bias, 0.f);
    }
}

// ---------------- launch ----------------

extern "C" void kernel_launch(void* const* d_in, const int* in_sizes, int n_in,
                              void* d_out, int out_size, void* d_ws, size_t ws_size,
                              hipStream_t stream) {
    const float* x      = (const float*)d_in[0];
    const int*   src    = (const int*)  d_in[1];
    const int*   dst    = (const int*)  d_in[2];
    const int*   ety    = (const int*)  d_in[3];
    const float* weight = (const float*)d_in[4];
    const float* w_comp = (const float*)d_in[5];
    const float* h_bias = (const float*)d_in[6];
    const float* loop_w = (const float*)d_in[7];
    float* out = (float*)d_out;

    int* deg    = (int*)d_ws;                 // N
    int* indptr = deg + N_NODES;              // N+1
    int* cursor = indptr + N_NODES + 1;       // N
    int* packed = cursor + N_NODES;           // E

    hipMemsetAsync(d_ws, 0, (size_t)(3 * N_NODES + 1) * sizeof(int), stream);

    k_hist<<<(N_EDGES + 255) / 256, 256, 0, stream>>>(dst, deg);
    k_scan<<<1, 1024, 0, stream>>>(deg, indptr);
    k_scatter<<<(N_EDGES + 255) / 256, 256, 0, stream>>>(dst, src, ety, indptr, cursor, packed);
    k_fused<<<N_NODES / NODES_PER_BLOCK, 256, 0, stream>>>(
        x, weight, w_comp, h_bias, loop_w, indptr, packed, out);
}

// Round 4
// 1489.260 us; speedup vs baseline: 1.8413x; 1.5422x over previous
//
#include <hip/hip_runtime.h>

#define N_NODES 50000
#define N_EDGES 1600000
#define NREL 32
#define NBASES 8
#define DIN 128
#define DOUT 128
#define KTOT (NBASES * DIN)       // 1024
#define KSL (KTOT + DIN)          // 1152 (self-loop folded in)
#define NODES_PER_BLOCK 8

// ---------------- CSR build ----------------

__global__ void k_hist(const int* __restrict__ dst, int* __restrict__ deg) {
    int e = blockIdx.x * blockDim.x + threadIdx.x;
    if (e < N_EDGES) atomicAdd(&deg[dst[e]], 1);
}

__global__ void k_scan(const int* __restrict__ deg, int* __restrict__ indptr) {
    __shared__ int sdata[1024];
    const int T = 1024;
    int t = threadIdx.x;
    const int chunk = (N_NODES + T - 1) / T;
    int lo = t * chunk;
    int hi = lo + chunk; if (hi > N_NODES) hi = N_NODES;
    if (lo > N_NODES) lo = N_NODES;
    int s = 0;
    for (int i = lo; i < hi; ++i) s += deg[i];
    sdata[t] = s;
    __syncthreads();
    for (int off = 1; off < T; off <<= 1) {
        int v = (t >= off) ? sdata[t - off] : 0;
        __syncthreads();
        sdata[t] += v;
        __syncthreads();
    }
    int base = (t == 0) ? 0 : sdata[t - 1];
    for (int i = lo; i < hi; ++i) { indptr[i] = base; base += deg[i]; }
    if (t == T - 1) indptr[N_NODES] = sdata[T - 1];
}

// writes dst-sorted packed records: src | (etype << 16)
__global__ void k_scatter(const int* __restrict__ dst,
                          const int* __restrict__ src,
                          const int* __restrict__ ety,
                          const int* __restrict__ indptr,
                          int* __restrict__ cursor,
                          int* __restrict__ packed) {
    int e = blockIdx.x * blockDim.x + threadIdx.x;
    if (e < N_EDGES) {
        int d = dst[e];
        int pos = atomicAdd(&cursor[d], 1);
        packed[indptr[d] + pos] = src[e] | (ety[e] << 16);
    }
}

// ---------------- fused aggregate + project ----------------
// Block: 256 threads (4 waves), 8 dst nodes.
// Phase 1: wave w aggregates nodes {w, w+4}; lane covers d=2*lane..2*lane+1
//          (float2). Edge records loaded 64-wide coalesced, broadcast via
//          __shfl. 4 x-row gathers in flight per iteration (ILP); w_comp
//          rows read from LDS immediately before use (wave-broadcast,
//          conflict-free) -- NOT batched into registers (that spilled).
// Phase 2: h = tmp[8 x 1152] @ [weight;loop_w][1152 x 128], weight read
//          straight from L2 (coalesced), tmp via LDS broadcast float4.

__device__ __forceinline__ void fma8(float2* acc, const float* __restrict__ wcrow,
                                     const float2 xv) {
    const float4 wA = *(const float4*)&wcrow[0];
    const float4 wB = *(const float4*)&wcrow[4];
    acc[0].x += wA.x * xv.x; acc[0].y += wA.x * xv.y;
    acc[1].x += wA.y * xv.x; acc[1].y += wA.y * xv.y;
    acc[2].x += wA.z * xv.x; acc[2].y += wA.z * xv.y;
    acc[3].x += wA.w * xv.x; acc[3].y += wA.w * xv.y;
    acc[4].x += wB.x * xv.x; acc[4].y += wB.x * xv.y;
    acc[5].x += wB.y * xv.x; acc[5].y += wB.y * xv.y;
    acc[6].x += wB.z * xv.x; acc[6].y += wB.z * xv.y;
    acc[7].x += wB.w * xv.x; acc[7].y += wB.w * xv.y;
}

__launch_bounds__(256, 2)
__global__ void k_fused(const float* __restrict__ x,
                        const float* __restrict__ weight,    // [1024][128]
                        const float* __restrict__ w_comp,    // [32][8]
                        const float* __restrict__ h_bias,    // [128]
                        const float* __restrict__ loop_w,    // [128][128]
                        const int* __restrict__ indptr,
                        const int* __restrict__ packed,
                        float* __restrict__ out) {
    __shared__ __align__(16) float wc[NREL * NBASES];            // 1 KB
    __shared__ __align__(16) float tmp[NODES_PER_BLOCK][KSL];    // 36 KB

    const int tid  = threadIdx.x;
    const int lane = tid & 63;
    const int wid  = tid >> 6;                 // 0..3
    const int nbase = blockIdx.x * NODES_PER_BLOCK;

    if (tid < NREL * NBASES) wc[tid] = w_comp[tid];
    __syncthreads();

    // ---- Phase 1 ----
    for (int rep = 0; rep < 2; ++rep) {
        const int nl = wid + rep * 4;
        const int node = nbase + nl;
        float2 acc[NBASES];
        #pragma unroll
        for (int b = 0; b < NBASES; ++b) acc[b] = make_float2(0.f, 0.f);

        if (node < N_NODES) {
            // self-loop row into LDS
            *(float2*)&tmp[nl][KTOT + 2 * lane] =
                *(const float2*)&x[(size_t)node * DIN + 2 * lane];

            const int beg = indptr[node], end = indptr[node + 1];
            for (int base = beg; base < end; base += 64) {
                const int cnt = min(64, end - base);
                int pk = 0;
                if (base + lane < end) pk = packed[base + lane];
                int j = 0;
                for (; j + 4 <= cnt; j += 4) {
                    const int p0 = __shfl(pk, j + 0);
                    const int p1 = __shfl(pk, j + 1);
                    const int p2 = __shfl(pk, j + 2);
                    const int p3 = __shfl(pk, j + 3);
                    // 4 independent gathers in flight
                    const float2 x0 = *(const float2*)&x[(size_t)(p0 & 0xFFFF) * DIN + 2 * lane];
                    const float2 x1 = *(const float2*)&x[(size_t)(p1 & 0xFFFF) * DIN + 2 * lane];
                    const float2 x2 = *(const float2*)&x[(size_t)(p2 & 0xFFFF) * DIN + 2 * lane];
                    const float2 x3 = *(const float2*)&x[(size_t)(p3 & 0xFFFF) * DIN + 2 * lane];
                    fma8(acc, &wc[(p0 >> 16) * NBASES], x0);
                    fma8(acc, &wc[(p1 >> 16) * NBASES], x1);
                    fma8(acc, &wc[(p2 >> 16) * NBASES], x2);
                    fma8(acc, &wc[(p3 >> 16) * NBASES], x3);
                }
                for (; j < cnt; ++j) {
                    const int p0 = __shfl(pk, j);
                    const float2 x0 = *(const float2*)&x[(size_t)(p0 & 0xFFFF) * DIN + 2 * lane];
                    fma8(acc, &wc[(p0 >> 16) * NBASES], x0);
                }
            }
        }
        #pragma unroll
        for (int b = 0; b < NBASES; ++b)
            *(float2*)&tmp[nl][b * DIN + 2 * lane] = acc[b];
    }
    __syncthreads();

    // ---- Phase 2: [8 x 1152] @ [1152 x 128] ----
    const int d = tid & 127;
    const int half = tid >> 7;
    float o[4] = {0.f, 0.f, 0.f, 0.f};     // nodes half, half+2, half+4, half+6

    for (int k = 0; k < KTOT; k += 4) {
        const float wv0 = weight[(k + 0) * DOUT + d];
        const float wv1 = weight[(k + 1) * DOUT + d];
        const float wv2 = weight[(k + 2) * DOUT + d];
        const float wv3 = weight[(k + 3) * DOUT + d];
        #pragma unroll
        for (int j = 0; j < 4; ++j) {
            const float4 t = *(const float4*)&tmp[half + 2 * j][k];
            o[j] += t.x * wv0 + t.y * wv1 + t.z * wv2 + t.w * wv3;
        }
    }
    for (int k = 0; k < DIN; k += 4) {
        const float wv0 = loop_w[(k + 0) * DOUT + d];
        const float wv1 = loop_w[(k + 1) * DOUT + d];
        const float wv2 = loop_w[(k + 2) * DOUT + d];
        const float wv3 = loop_w[(k + 3) * DOUT + d];
        #pragma unroll
        for (int j = 0; j < 4; ++j) {
            const float4 t = *(const float4*)&tmp[half + 2 * j][KTOT + k];
            o[j] += t.x * wv0 + t.y * wv1 + t.z * wv2 + t.w * wv3;
        }
    }

    const float bias = h_bias[d];
    #pragma unroll
    for (int j = 0; j < 4; ++j) {
        const int node = nbase + half + 2 * j;
        if (node < N_NODES)
            out[(size_t)node * DOUT + d] = fmaxf(o[j] + bias, 0.f);
    }
}

// ---------------- launch ----------------

extern "C" void kernel_launch(void* const* d_in, const int* in_sizes, int n_in,
                              void* d_out, int out_size, void* d_ws, size_t ws_size,
                              hipStream_t stream) {
    const float* x      = (const float*)d_in[0];
    const int*   src    = (const int*)  d_in[1];
    const int*   dst    = (const int*)  d_in[2];
    const int*   ety    = (const int*)  d_in[3];
    const float* weight = (const float*)d_in[4];
    const float* w_comp = (const float*)d_in[5];
    const float* h_bias = (const float*)d_in[6];
    const float* loop_w = (const float*)d_in[7];
    float* out = (float*)d_out;

    int* deg    = (int*)d_ws;                 // N
    int* indptr = deg + N_NODES;              // N+1
    int* cursor = indptr + N_NODES + 1;       // N
    int* packed = cursor + N_NODES;           // E

    hipMemsetAsync(d_ws, 0, (size_t)(3 * N_NODES + 1) * sizeof(int), stream);

    k_hist<<<(N_EDGES + 255) / 256, 256, 0, stream>>>(dst, deg);
    k_scan<<<1, 1024, 0, stream>>>(deg, indptr);
    k_scatter<<<(N_EDGES + 255) / 256, 256, 0, stream>>>(dst, src, ety, indptr, cursor, packed);
    k_fused<<<N_NODES / NODES_PER_BLOCK, 256, 0, stream>>>(
        x, weight, w_comp, h_bias, loop_w, indptr, packed, out);
}